// Round 1
// baseline (1644.590 us; speedup 1.0000x reference)
//
#include <hip/hip_runtime.h>
#include <math.h>

// FlowLayer: 2 steps of manifold (S^2) graph heat flow.
// N=50000 nodes, C=16 channels, D=3, E=1.6M edges.
// Layout of x/agg: [N, C, D] row-major, node row = 48 floats (192 B).

constexpr float EPS64F = 2.2204460492503131e-16f;  // np.float64 eps

__global__ __launch_bounds__(256) void deg_kernel(
    const float* __restrict__ ew, const int* __restrict__ snd,
    float* __restrict__ deg, int E) {
  int e = blockIdx.x * 256 + threadIdx.x;
  if (e < E) atomicAdd(&deg[snd[e]], ew[e]);
}

// thread t -> edge e = t>>4, channel c = t&15.
// Lanes 0..15 cover channels of one edge => contiguous 192B row reads.
__global__ __launch_bounds__(256) void edge_kernel(
    const float* __restrict__ x, const float* __restrict__ ew,
    const int* __restrict__ snd, const int* __restrict__ rcv,
    float* __restrict__ agg, int E) {
  unsigned int t = blockIdx.x * 256u + threadIdx.x;
  int c = (int)(t & 15u);
  int e = (int)(t >> 4);
  if (e >= E) return;
  int s = snd[e];
  int r = rcv[e];
  float w = ew[e];
  int ip = s * 48 + c * 3;
  int iq = r * 48 + c * 3;
  float p0 = x[ip + 0], p1 = x[ip + 1], p2 = x[ip + 2];
  float q0 = x[iq + 0], q1 = x[iq + 1], q2 = x[iq + 2];
  float cs = p0 * q0 + p1 * q1 + p2 * q2;
  cs = fminf(1.0f, fmaxf(-1.0f, cs));
  float u0 = q0 - cs * p0;
  float u1 = q1 - cs * p1;
  float u2 = q2 - cs * p2;
  float un = sqrtf(u0 * u0 + u1 * u1 + u2 * u2);
  float theta = acosf(cs);
  float coef = w * theta / (un + 1e-12f);
  atomicAdd(&agg[ip + 0], coef * u0);
  atomicAdd(&agg[ip + 1], coef * u1);
  atomicAdd(&agg[ip + 2], coef * u2);
}

// thread t -> node n = t>>4, channel c = t&15.
// v_lap = -agg/deg; nrm/scale are sign-invariant; -(v_lap*scale)*t = +g*scale*t.
__global__ __launch_bounds__(256) void update_kernel(
    const float* __restrict__ xin, const float* __restrict__ agg,
    const float* __restrict__ deg, const float* __restrict__ tsq,
    const float* __restrict__ dsq, float* __restrict__ xout, int N) {
  unsigned int t = blockIdx.x * 256u + threadIdx.x;
  int c = (int)(t & 15u);
  int n = (int)(t >> 4);
  if (n >= N) return;
  float invdg = 1.0f / (deg[n] + 1e-12f);
  int idx = n * 48 + c * 3;
  float g0 = agg[idx + 0] * invdg;
  float g1 = agg[idx + 1] * invdg;
  float g2 = agg[idx + 2] * invdg;
  float nrm = sqrtf(g0 * g0 + g1 * g1 + g2 * g2 + EPS64F);
  float ts = tsq[c];
  float tch = ts * ts * 0.5f;         // t_sqrt^2 / N_STEPS, N_STEPS = 2
  float dsv = dsq[c];
  float dch = dsv * dsv;              // delta_sqrt^2
  float alp = 1.0f / (1.0f + expf(dch - nrm));   // sigmoid(nrm - delta)
  float scale = (nrm * alp <= 1.0f) ? alp : (1.0f / nrm);  // MAX_STEP = 1
  float f = scale * tch;
  float v0 = g0 * f, v1 = g1 * f, v2 = g2 * f;
  float p0 = xin[idx + 0], p1 = xin[idx + 1], p2 = xin[idx + 2];
  float nv = sqrtf(v0 * v0 + v1 * v1 + v2 * v2);
  float cn = cosf(nv);
  float sc = (nv > 1e-20f) ? (sinf(nv) / nv) : 1.0f;  // sinc
  float y0 = cn * p0 + sc * v0;
  float y1 = cn * p1 + sc * v1;
  float y2 = cn * p2 + sc * v2;
  float inv = rsqrtf(y0 * y0 + y1 * y1 + y2 * y2);
  xout[idx + 0] = y0 * inv;
  xout[idx + 1] = y1 * inv;
  xout[idx + 2] = y2 * inv;
}

extern "C" void kernel_launch(void* const* d_in, const int* in_sizes, int n_in,
                              void* d_out, int out_size, void* d_ws, size_t ws_size,
                              hipStream_t stream) {
  const float* nodes = (const float*)d_in[0];  // [N,16,3]
  const float* ew    = (const float*)d_in[1];  // [E]
  const float* tsq   = (const float*)d_in[2];  // [16]
  const float* dsq   = (const float*)d_in[3];  // [16]
  const int*   snd   = (const int*)d_in[4];    // [E]
  const int*   rcv   = (const int*)d_in[5];    // [E]
  float* out = (float*)d_out;

  int E = in_sizes[1];
  int N = in_sizes[0] / 48;

  // workspace: deg [N] floats, agg [N*48] floats  (~9.8 MB)
  float* deg = (float*)d_ws;
  float* agg = deg + N;

  hipMemsetAsync(deg, 0, sizeof(float) * (size_t)N, stream);
  hipMemsetAsync(agg, 0, sizeof(float) * (size_t)N * 48, stream);

  int deg_blocks  = (E + 255) / 256;
  int edge_blocks = (int)(((long long)E * 16 + 255) / 256);
  int node_blocks = (N * 16 + 255) / 256;

  deg_kernel<<<deg_blocks, 256, 0, stream>>>(ew, snd, deg, E);

  // step 1: nodes -> out
  edge_kernel<<<edge_blocks, 256, 0, stream>>>(nodes, ew, snd, rcv, agg, E);
  update_kernel<<<node_blocks, 256, 0, stream>>>(nodes, agg, deg, tsq, dsq, out, N);

  // step 2: out -> out (in-place safe: pointwise per (n,c))
  hipMemsetAsync(agg, 0, sizeof(float) * (size_t)N * 48, stream);
  edge_kernel<<<edge_blocks, 256, 0, stream>>>(out, ew, snd, rcv, agg, E);
  update_kernel<<<node_blocks, 256, 0, stream>>>(out, agg, deg, tsq, dsq, out, N);
}

// Round 2
// 598.706 us; speedup vs baseline: 2.7469x; 2.7469x over previous
//
#include <hip/hip_runtime.h>
#include <math.h>

// FlowLayer: 2 steps of manifold (S^2) graph heat flow.
// N=50000 nodes, C=16 channels, D=3, E=1.6M edges.
// Strategy: build CSR by sender once per call (key is step-invariant), then
// each step = one fused gather+update kernel, zero fp32 atomics.

constexpr float EPS64F = 2.2204460492503131e-16f;  // np.float64 eps

__global__ __launch_bounds__(256) void hist_kernel(
    const float* __restrict__ ew, const int* __restrict__ snd,
    float* __restrict__ deg, int* __restrict__ counts, int E) {
  int e = blockIdx.x * 256 + threadIdx.x;
  if (e < E) {
    int s = snd[e];
    atomicAdd(&counts[s], 1);
    atomicAdd(&deg[s], ew[e]);
  }
}

// Single-block exclusive scan of counts[N] -> row_start[N+1] (Hillis-Steele tiles).
__global__ __launch_bounds__(1024) void scan_kernel(
    const int* __restrict__ counts, int* __restrict__ row_start, int N) {
  __shared__ int sh[1024];
  __shared__ int run_sh;
  int tid = threadIdx.x;
  if (tid == 0) run_sh = 0;
  __syncthreads();
  for (int base = 0; base < N; base += 1024) {
    int i = base + tid;
    int v = (i < N) ? counts[i] : 0;
    sh[tid] = v;
    __syncthreads();
    for (int off = 1; off < 1024; off <<= 1) {
      int t = (tid >= off) ? sh[tid - off] : 0;
      __syncthreads();
      sh[tid] += t;
      __syncthreads();
    }
    int incl = sh[tid];
    int run = run_sh;
    if (i < N) row_start[i] = run + incl - v;  // exclusive
    __syncthreads();
    if (tid == 1023) run_sh = run + incl;
    __syncthreads();
  }
  if (tid == 0) row_start[N] = run_sh;
}

// Scatter edges into CSR order; store rcv and w directly (contiguous inner loop).
__global__ __launch_bounds__(256) void fill_kernel(
    const int* __restrict__ snd, const int* __restrict__ rcv,
    const float* __restrict__ ew, const int* __restrict__ row_start,
    int* __restrict__ cursor, int* __restrict__ prcv, float* __restrict__ pw,
    int E) {
  int e = blockIdx.x * 256 + threadIdx.x;
  if (e < E) {
    int s = snd[e];
    int pos = atomicAdd(&cursor[s], 1);
    int o = row_start[s] + pos;
    prcv[o] = rcv[e];
    pw[o] = ew[e];
  }
}

// Fused: per (node, channel) gather log-maps over adjacency, then step update.
// c in low 4 bits => 16 lanes read one contiguous 192B node row.
__global__ __launch_bounds__(256) void flow_kernel(
    const float* __restrict__ xin, const float* __restrict__ deg,
    const int* __restrict__ row_start, const int* __restrict__ prcv,
    const float* __restrict__ pw, const float* __restrict__ tsq,
    const float* __restrict__ dsq, float* __restrict__ xout, int N) {
  unsigned int t = blockIdx.x * 256u + threadIdx.x;
  int c = (int)(t & 15u);
  int n = (int)(t >> 4);
  if (n >= N) return;
  int beg = row_start[n];
  int end = row_start[n + 1];
  int ip = n * 48 + c * 3;
  float p0 = xin[ip + 0], p1 = xin[ip + 1], p2 = xin[ip + 2];
  float a0 = 0.f, a1 = 0.f, a2 = 0.f;
  for (int j = beg; j < end; ++j) {
    int r = prcv[j];
    float w = pw[j];
    int iq = r * 48 + c * 3;
    float q0 = xin[iq + 0], q1 = xin[iq + 1], q2 = xin[iq + 2];
    float cs = fminf(1.0f, fmaxf(-1.0f, p0 * q0 + p1 * q1 + p2 * q2));
    float u0 = q0 - cs * p0;
    float u1 = q1 - cs * p1;
    float u2 = q2 - cs * p2;
    float un = sqrtf(u0 * u0 + u1 * u1 + u2 * u2);
    float coef = w * acosf(cs) / (un + 1e-12f);
    a0 += coef * u0;
    a1 += coef * u1;
    a2 += coef * u2;
  }
  // v_lap = -agg/deg; nrm/scale sign-invariant; -(v_lap*scale)*t = +g*scale*t
  float invdg = 1.0f / (deg[n] + 1e-12f);
  float g0 = a0 * invdg, g1 = a1 * invdg, g2 = a2 * invdg;
  float nrm = sqrtf(g0 * g0 + g1 * g1 + g2 * g2 + EPS64F);
  float ts = tsq[c];
  float tch = ts * ts * 0.5f;  // t_sqrt^2 / N_STEPS
  float dsv = dsq[c];
  float dch = dsv * dsv;
  float alp = 1.0f / (1.0f + expf(dch - nrm));             // sigmoid(nrm - delta)
  float scale = (nrm * alp <= 1.0f) ? alp : (1.0f / nrm);  // MAX_STEP = 1
  float f = scale * tch;
  float v0 = g0 * f, v1 = g1 * f, v2 = g2 * f;
  float nv = sqrtf(v0 * v0 + v1 * v1 + v2 * v2);
  float cn = cosf(nv);
  float sc = (nv > 1e-20f) ? (sinf(nv) / nv) : 1.0f;  // sinc
  float y0 = cn * p0 + sc * v0;
  float y1 = cn * p1 + sc * v1;
  float y2 = cn * p2 + sc * v2;
  float inv = rsqrtf(y0 * y0 + y1 * y1 + y2 * y2);
  xout[ip + 0] = y0 * inv;
  xout[ip + 1] = y1 * inv;
  xout[ip + 2] = y2 * inv;
}

extern "C" void kernel_launch(void* const* d_in, const int* in_sizes, int n_in,
                              void* d_out, int out_size, void* d_ws, size_t ws_size,
                              hipStream_t stream) {
  const float* nodes = (const float*)d_in[0];  // [N,16,3]
  const float* ew    = (const float*)d_in[1];  // [E]
  const float* tsq   = (const float*)d_in[2];  // [16]
  const float* dsq   = (const float*)d_in[3];  // [16]
  const int*   snd   = (const int*)d_in[4];    // [E]
  const int*   rcv   = (const int*)d_in[5];    // [E]
  float* out = (float*)d_out;

  int E = in_sizes[1];
  int N = in_sizes[0] / 48;

  // workspace layout (all 4-byte elems):
  // deg[N] | counts[N] | row_start[N+1] | prcv[E] | pw[E] | xtmp[N*48]
  float* deg       = (float*)d_ws;
  int*   counts    = (int*)(deg + N);
  int*   row_start = counts + N;
  int*   prcv      = row_start + (N + 1);
  float* pw        = (float*)(prcv + E);
  float* xtmp      = pw + E;

  // zero deg + counts in one memset (contiguous)
  hipMemsetAsync(deg, 0, sizeof(float) * (size_t)(2 * N), stream);

  int eb = (E + 255) / 256;
  int fb = (N * 16 + 255) / 256;

  hist_kernel<<<eb, 256, 0, stream>>>(ew, snd, deg, counts, E);
  scan_kernel<<<1, 1024, 0, stream>>>(counts, row_start, N);
  hipMemsetAsync(counts, 0, sizeof(int) * (size_t)N, stream);  // reuse as cursor
  fill_kernel<<<eb, 256, 0, stream>>>(snd, rcv, ew, row_start, counts, prcv, pw, E);

  // step 1: nodes -> xtmp ; step 2: xtmp -> out (not in-place: reads neighbors)
  flow_kernel<<<fb, 256, 0, stream>>>(nodes, deg, row_start, prcv, pw, tsq, dsq, xtmp, N);
  flow_kernel<<<fb, 256, 0, stream>>>(xtmp, deg, row_start, prcv, pw, tsq, dsq, out, N);
}

// Round 3
// 392.459 us; speedup vs baseline: 4.1905x; 1.5255x over previous
//
#include <hip/hip_runtime.h>
#include <math.h>

// FlowLayer: 2 steps of manifold (S^2) graph heat flow.
// N=50000 nodes, C=16 channels, D=3, E=1.6M edges.
// CSR built once per call with exactly ONE atomic per edge:
//   hist: pos[e] = atomicAdd(counts[snd[e]],1)   (slot = return value)
//   scan: counts -> row_start (wave-shfl scan)
//   fill: prcv/pw[row_start[s]+pos[e]] = rcv/ew  (no atomics)
// deg is folded into the flow kernel (sum of pw over the row, loaded anyway).

constexpr float EPS64F = 2.2204460492503131e-16f;  // np.float64 eps

__global__ __launch_bounds__(256) void hist_kernel(
    const int* __restrict__ snd, int* __restrict__ counts,
    int* __restrict__ pos, int E) {
  int e = blockIdx.x * 256 + threadIdx.x;
  if (e < E) pos[e] = atomicAdd(&counts[snd[e]], 1);
}

// Single-block scan: 16 waves x shfl-scan, 3 barriers per 1024-tile.
__global__ __launch_bounds__(1024) void scan_kernel(
    const int* __restrict__ counts, int* __restrict__ row_start, int N) {
  __shared__ int wsum[16];
  int tid = threadIdx.x;
  int lane = tid & 63, wave = tid >> 6;
  int run = 0;  // uniform across threads
  for (int base = 0; base < N; base += 1024) {
    int i = base + tid;
    int v = (i < N) ? counts[i] : 0;
    int incl = v;
    #pragma unroll
    for (int off = 1; off < 64; off <<= 1) {
      int t = __shfl_up(incl, off, 64);
      if (lane >= off) incl += t;
    }
    if (lane == 63) wsum[wave] = incl;
    __syncthreads();
    if (wave == 0 && lane < 16) {
      int wincl = wsum[lane];
      #pragma unroll
      for (int off = 1; off < 16; off <<= 1) {
        int t = __shfl_up(wincl, off, 64);
        if (lane >= off) wincl += t;
      }
      wsum[lane] = wincl;  // inclusive over wave totals
    }
    __syncthreads();
    int woff = (wave > 0) ? wsum[wave - 1] : 0;
    int tile_total = wsum[15];
    if (i < N) row_start[i] = run + woff + incl - v;  // exclusive
    run += tile_total;
    __syncthreads();  // wsum reused next tile
  }
  if (tid == 0) row_start[N] = run;
}

__global__ __launch_bounds__(256) void fill_kernel(
    const int* __restrict__ snd, const int* __restrict__ rcv,
    const float* __restrict__ ew, const int* __restrict__ row_start,
    const int* __restrict__ pos, int* __restrict__ prcv,
    float* __restrict__ pw, int E) {
  int e = blockIdx.x * 256 + threadIdx.x;
  if (e < E) {
    int o = row_start[snd[e]] + pos[e];
    prcv[o] = rcv[e];
    pw[o] = ew[e];
  }
}

// Fused: per (node, channel) gather log-maps over adjacency, then step update.
// c in low 4 bits => 16 lanes read one contiguous 192B node row.
__global__ __launch_bounds__(256) void flow_kernel(
    const float* __restrict__ xin, const int* __restrict__ row_start,
    const int* __restrict__ prcv, const float* __restrict__ pw,
    const float* __restrict__ tsq, const float* __restrict__ dsq,
    float* __restrict__ xout, int N) {
  unsigned int t = blockIdx.x * 256u + threadIdx.x;
  int c = (int)(t & 15u);
  int n = (int)(t >> 4);
  if (n >= N) return;
  int beg = row_start[n];
  int end = row_start[n + 1];
  int ip = n * 48 + c * 3;
  float p0 = xin[ip + 0], p1 = xin[ip + 1], p2 = xin[ip + 2];
  float a0 = 0.f, a1 = 0.f, a2 = 0.f, wsum = 0.f;
  for (int j = beg; j < end; ++j) {
    int r = prcv[j];
    float w = pw[j];
    int iq = r * 48 + c * 3;
    float q0 = xin[iq + 0], q1 = xin[iq + 1], q2 = xin[iq + 2];
    float cs = fminf(1.0f, fmaxf(-1.0f, p0 * q0 + p1 * q1 + p2 * q2));
    float u0 = q0 - cs * p0;
    float u1 = q1 - cs * p1;
    float u2 = q2 - cs * p2;
    float un = sqrtf(u0 * u0 + u1 * u1 + u2 * u2);
    float coef = w * acosf(cs) / (un + 1e-12f);
    a0 += coef * u0;
    a1 += coef * u1;
    a2 += coef * u2;
    wsum += w;
  }
  // v_lap = -agg/deg; nrm/scale sign-invariant; -(v_lap*scale)*t = +g*scale*t
  float invdg = 1.0f / (wsum + 1e-12f);
  float g0 = a0 * invdg, g1 = a1 * invdg, g2 = a2 * invdg;
  float nrm = sqrtf(g0 * g0 + g1 * g1 + g2 * g2 + EPS64F);
  float ts = tsq[c];
  float tch = ts * ts * 0.5f;  // t_sqrt^2 / N_STEPS
  float dsv = dsq[c];
  float dch = dsv * dsv;
  float alp = 1.0f / (1.0f + expf(dch - nrm));             // sigmoid(nrm - delta)
  float scale = (nrm * alp <= 1.0f) ? alp : (1.0f / nrm);  // MAX_STEP = 1
  float f = scale * tch;
  float v0 = g0 * f, v1 = g1 * f, v2 = g2 * f;
  float nv = sqrtf(v0 * v0 + v1 * v1 + v2 * v2);
  float cn = cosf(nv);
  float sc = (nv > 1e-20f) ? (sinf(nv) / nv) : 1.0f;  // sinc
  float y0 = cn * p0 + sc * v0;
  float y1 = cn * p1 + sc * v1;
  float y2 = cn * p2 + sc * v2;
  float inv = rsqrtf(y0 * y0 + y1 * y1 + y2 * y2);
  xout[ip + 0] = y0 * inv;
  xout[ip + 1] = y1 * inv;
  xout[ip + 2] = y2 * inv;
}

extern "C" void kernel_launch(void* const* d_in, const int* in_sizes, int n_in,
                              void* d_out, int out_size, void* d_ws, size_t ws_size,
                              hipStream_t stream) {
  const float* nodes = (const float*)d_in[0];  // [N,16,3]
  const float* ew    = (const float*)d_in[1];  // [E]
  const float* tsq   = (const float*)d_in[2];  // [16]
  const float* dsq   = (const float*)d_in[3];  // [16]
  const int*   snd   = (const int*)d_in[4];    // [E]
  const int*   rcv   = (const int*)d_in[5];    // [E]
  float* out = (float*)d_out;

  int E = in_sizes[1];
  int N = in_sizes[0] / 48;

  // workspace (4-byte elems):
  // counts[N] | row_start[N+1] | prcv[E] | pw[E] | Z
  // Z is a union: pos[E] (live hist->fill) and xtmp[N*48] (live during flow)
  int*   counts    = (int*)d_ws;
  int*   row_start = counts + N;
  int*   prcv      = row_start + (N + 1);
  float* pw        = (float*)(prcv + E);
  int*   pos       = (int*)(pw + E);
  float* xtmp      = (float*)pos;  // aliased; lifetimes disjoint

  hipMemsetAsync(counts, 0, sizeof(int) * (size_t)N, stream);

  int eb = (E + 255) / 256;
  int fb = (N * 16 + 255) / 256;

  hist_kernel<<<eb, 256, 0, stream>>>(snd, counts, pos, E);
  scan_kernel<<<1, 1024, 0, stream>>>(counts, row_start, N);
  fill_kernel<<<eb, 256, 0, stream>>>(snd, rcv, ew, row_start, pos, prcv, pw, E);

  // step 1: nodes -> xtmp ; step 2: xtmp -> out (not in-place: reads neighbors)
  flow_kernel<<<fb, 256, 0, stream>>>(nodes, row_start, prcv, pw, tsq, dsq, xtmp, N);
  flow_kernel<<<fb, 256, 0, stream>>>(xtmp, row_start, prcv, pw, tsq, dsq, out, N);
}

// Round 4
// 323.136 us; speedup vs baseline: 5.0895x; 1.2145x over previous
//
#include <hip/hip_runtime.h>
#include <math.h>

// FlowLayer: 2 steps of manifold (S^2) graph heat flow.
// N=50000 nodes, C=16 channels, D=3, E=1.6M edges.
// CSR build: 1 atomic/edge (hist), 3-phase scan, atomic-free fill with
// packed (rcv,w) int2 -> one 8B scatter per edge.
// Flow: fused gather+update, fast acos poly + v_rsq/v_rcp (threshold 2e-2).

constexpr float EPS64F = 2.2204460492503131e-16f;  // np.float64 eps
constexpr float PI_F   = 3.14159265358979323846f;

__global__ __launch_bounds__(256) void hist_kernel(
    const int* __restrict__ snd, int* __restrict__ counts,
    int* __restrict__ pos, int E) {
  int e = blockIdx.x * 256 + threadIdx.x;
  if (e < E) pos[e] = atomicAdd(&counts[snd[e]], 1);
}

// Phase A: per-1024 tile exclusive scan (wave shfl), tile totals to btot.
__global__ __launch_bounds__(1024) void scanA_kernel(
    const int* __restrict__ counts, int* __restrict__ row_start,
    int* __restrict__ btot, int N) {
  __shared__ int wsum[16];
  int tid = threadIdx.x;
  int lane = tid & 63, wave = tid >> 6;
  int i = blockIdx.x * 1024 + tid;
  int v = (i < N) ? counts[i] : 0;
  int incl = v;
  #pragma unroll
  for (int off = 1; off < 64; off <<= 1) {
    int t = __shfl_up(incl, off, 64);
    if (lane >= off) incl += t;
  }
  if (lane == 63) wsum[wave] = incl;
  __syncthreads();
  if (wave == 0 && lane < 16) {
    int wincl = wsum[lane];
    #pragma unroll
    for (int off = 1; off < 16; off <<= 1) {
      int t = __shfl_up(wincl, off, 64);
      if (lane >= off) wincl += t;
    }
    wsum[lane] = wincl;  // inclusive over wave totals
  }
  __syncthreads();
  int woff = (wave > 0) ? wsum[wave - 1] : 0;
  if (i < N) row_start[i] = woff + incl - v;  // tile-local exclusive
  if (tid == 0) btot[blockIdx.x] = wsum[15];
}

// Phase B: one wave scans block totals (nb <= 64); writes exclusive offsets
// and the grand total into row_start[N].
__global__ __launch_bounds__(64) void scanB_kernel(
    const int* __restrict__ btot, int* __restrict__ boff,
    int* __restrict__ row_start, int nb, int N) {
  int lane = threadIdx.x;
  int v = (lane < nb) ? btot[lane] : 0;
  int incl = v;
  #pragma unroll
  for (int off = 1; off < 64; off <<= 1) {
    int t = __shfl_up(incl, off, 64);
    if (lane >= off) incl += t;
  }
  if (lane < nb) boff[lane] = incl - v;
  if (lane == 63) row_start[N] = incl;  // grand total
}

// Phase C: add block offsets.
__global__ __launch_bounds__(1024) void scanC_kernel(
    int* __restrict__ row_start, const int* __restrict__ boff, int N) {
  int i = blockIdx.x * 1024 + threadIdx.x;
  if (i < N) row_start[i] += boff[blockIdx.x];
}

// Atomic-free fill: one 8B scatter per edge.
__global__ __launch_bounds__(256) void fill_kernel(
    const int* __restrict__ snd, const int* __restrict__ rcv,
    const float* __restrict__ ew, const int* __restrict__ row_start,
    const int* __restrict__ pos, int2* __restrict__ pair, int E) {
  int e = blockIdx.x * 256 + threadIdx.x;
  if (e < E) {
    int o = row_start[snd[e]] + pos[e];
    pair[o] = make_int2(rcv[e], __float_as_int(ew[e]));
  }
}

// Fused: per (node, channel) gather log-maps over adjacency, then step update.
// c in low 4 bits => 16 lanes read one contiguous 192B node row.
__global__ __launch_bounds__(256) void flow_kernel(
    const float* __restrict__ xin, const int* __restrict__ row_start,
    const int2* __restrict__ pair, const float* __restrict__ tsq,
    const float* __restrict__ dsq, float* __restrict__ xout, int N) {
  unsigned int t = blockIdx.x * 256u + threadIdx.x;
  int c = (int)(t & 15u);
  int n = (int)(t >> 4);
  if (n >= N) return;
  int beg = row_start[n];
  int end = row_start[n + 1];
  int ip = n * 48 + c * 3;
  float p0 = xin[ip + 0], p1 = xin[ip + 1], p2 = xin[ip + 2];
  float a0 = 0.f, a1 = 0.f, a2 = 0.f, wsum = 0.f;
  for (int j = beg; j < end; ++j) {
    int2 pr = pair[j];
    int r = pr.x;
    float w = __int_as_float(pr.y);
    int iq = r * 48 + c * 3;
    float q0 = xin[iq + 0], q1 = xin[iq + 1], q2 = xin[iq + 2];
    float cs = fminf(1.0f, fmaxf(-1.0f, fmaf(p0, q0, fmaf(p1, q1, p2 * q2))));
    float u0 = fmaf(-cs, p0, q0);
    float u1 = fmaf(-cs, p1, q1);
    float u2 = fmaf(-cs, p2, q2);
    float un2 = fmaf(u0, u0, fmaf(u1, u1, u2 * u2));
    // acos via A&S 4.4.46: acos(x) = sqrt(1-x) * P(x) on [0,1], |err|<=2e-8
    float ax = fabsf(cs);
    float s = sqrtf(fmaxf(1.0f - ax, 0.0f));
    float poly = fmaf(ax,
        fmaf(ax, fmaf(ax, fmaf(ax, fmaf(ax, fmaf(ax,
            fmaf(ax, -0.0012624911f, 0.0066700901f),
            -0.0170881256f), 0.0308918810f), -0.0501743046f),
            0.0889789874f), -0.2145988016f), 1.5707963050f);
    float th = s * poly;
    float theta = (cs >= 0.0f) ? th : (PI_F - th);
    // theta * u / |u|  ==  theta * u * rsqrt(un2)
    float coef = w * theta * __builtin_amdgcn_rsqf(fmaxf(un2, 1e-24f));
    a0 = fmaf(coef, u0, a0);
    a1 = fmaf(coef, u1, a1);
    a2 = fmaf(coef, u2, a2);
    wsum += w;
  }
  // v_lap = -agg/deg; nrm/scale sign-invariant; -(v_lap*scale)*t = +g*scale*t
  float invdg = __builtin_amdgcn_rcpf(wsum + 1e-12f);
  float g0 = a0 * invdg, g1 = a1 * invdg, g2 = a2 * invdg;
  float nrm = sqrtf(fmaf(g0, g0, fmaf(g1, g1, g2 * g2)) + EPS64F);
  float ts = tsq[c];
  float tch = ts * ts * 0.5f;  // t_sqrt^2 / N_STEPS
  float dsv = dsq[c];
  float dch = dsv * dsv;
  float alp = __builtin_amdgcn_rcpf(1.0f + __expf(dch - nrm));  // sigmoid
  float scale = (nrm * alp <= 1.0f) ? alp : __builtin_amdgcn_rcpf(nrm);
  float f = scale * tch;
  float v0 = g0 * f, v1 = g1 * f, v2 = g2 * f;
  float nv = sqrtf(fmaf(v0, v0, fmaf(v1, v1, v2 * v2)));
  float cn = __cosf(nv);
  float sc = (nv > 1e-20f) ? (__sinf(nv) * __builtin_amdgcn_rcpf(nv)) : 1.0f;
  float y0 = fmaf(cn, p0, sc * v0);
  float y1 = fmaf(cn, p1, sc * v1);
  float y2 = fmaf(cn, p2, sc * v2);
  float inv = __builtin_amdgcn_rsqf(fmaf(y0, y0, fmaf(y1, y1, y2 * y2)));
  xout[ip + 0] = y0 * inv;
  xout[ip + 1] = y1 * inv;
  xout[ip + 2] = y2 * inv;
}

extern "C" void kernel_launch(void* const* d_in, const int* in_sizes, int n_in,
                              void* d_out, int out_size, void* d_ws, size_t ws_size,
                              hipStream_t stream) {
  const float* nodes = (const float*)d_in[0];  // [N,16,3]
  const float* ew    = (const float*)d_in[1];  // [E]
  const float* tsq   = (const float*)d_in[2];  // [16]
  const float* dsq   = (const float*)d_in[3];  // [16]
  const int*   snd   = (const int*)d_in[4];    // [E]
  const int*   rcv   = (const int*)d_in[5];    // [E]
  float* out = (float*)d_out;

  int E = in_sizes[1];
  int N = in_sizes[0] / 48;

  // workspace (4-byte elems):
  // counts[N] | row_start[N+1] | btot[64] | boff[64] | pair[2E] | Z
  // Z union: pos[E] (hist->fill) and xtmp[N*48] (flow1->flow2)
  int*   counts    = (int*)d_ws;
  int*   row_start = counts + N;
  int*   btot      = row_start + (N + 1);
  int*   boff      = btot + 64;
  int2*  pair      = (int2*)(boff + 64);
  int*   pos       = (int*)(pair + E);
  float* xtmp      = (float*)pos;  // aliased; lifetimes disjoint

  hipMemsetAsync(counts, 0, sizeof(int) * (size_t)N, stream);

  int eb = (E + 255) / 256;
  int nb = (N + 1023) / 1024;
  int fb = (N * 16 + 255) / 256;

  hist_kernel<<<eb, 256, 0, stream>>>(snd, counts, pos, E);
  scanA_kernel<<<nb, 1024, 0, stream>>>(counts, row_start, btot, N);
  scanB_kernel<<<1, 64, 0, stream>>>(btot, boff, row_start, nb, N);
  scanC_kernel<<<nb, 1024, 0, stream>>>(row_start, boff, N);
  fill_kernel<<<eb, 256, 0, stream>>>(snd, rcv, ew, row_start, pos, pair, E);

  // step 1: nodes -> xtmp ; step 2: xtmp -> out (not in-place: reads neighbors)
  flow_kernel<<<fb, 256, 0, stream>>>(nodes, row_start, pair, tsq, dsq, xtmp, N);
  flow_kernel<<<fb, 256, 0, stream>>>(xtmp, row_start, pair, tsq, dsq, out, N);
}

// Round 6
// 301.642 us; speedup vs baseline: 5.4521x; 1.0713x over previous
//
#include <hip/hip_runtime.h>
#include <math.h>

// FlowLayer: 2 steps of manifold (S^2) graph heat flow.
// N=50000 nodes, C=16 channels, D=3, E=1.6M edges.
// CSR build: 1 atomic/edge (hist, 4-wide), 3-phase scan, atomic-free fill
// with packed (rcv,w) 8B scatter. Flow: 1 wave per node, lane=(k*16+c),
// 8 edges per wave-iter (4 slots x 2-unroll), shfl_xor k-reduction.
// NOTE: |u|^2 MUST be computed from u's components (not 1-cs^2): near
// antipodal pairs 1-cs^2 cancels catastrophically -> rsq explodes (R5 bug).

constexpr float EPS64F = 2.2204460492503131e-16f;  // np.float64 eps
constexpr float PI_F   = 3.14159265358979323846f;

typedef int   vi4 __attribute__((ext_vector_type(4)));
typedef float vf4 __attribute__((ext_vector_type(4)));

__global__ __launch_bounds__(256) void hist_kernel(
    const vi4* __restrict__ snd4, int* __restrict__ counts,
    vi4* __restrict__ pos4, const int* __restrict__ snd,
    int* __restrict__ pos, int E) {
  int i = blockIdx.x * 256 + threadIdx.x;
  int E4 = E >> 2;
  if (i < E4) {
    vi4 s = __builtin_nontemporal_load(&snd4[i]);
    vi4 p;
    p.x = atomicAdd(&counts[s.x], 1);
    p.y = atomicAdd(&counts[s.y], 1);
    p.z = atomicAdd(&counts[s.z], 1);
    p.w = atomicAdd(&counts[s.w], 1);
    __builtin_nontemporal_store(p, &pos4[i]);
  }
  if (i == 0) {  // scalar tail (E % 4)
    for (int e = E4 << 2; e < E; ++e) pos[e] = atomicAdd(&counts[snd[e]], 1);
  }
}

// Phase A: per-1024 tile exclusive scan (wave shfl), tile totals to btot.
__global__ __launch_bounds__(1024) void scanA_kernel(
    const int* __restrict__ counts, int* __restrict__ row_start,
    int* __restrict__ btot, int N) {
  __shared__ int wsum[16];
  int tid = threadIdx.x;
  int lane = tid & 63, wave = tid >> 6;
  int i = blockIdx.x * 1024 + tid;
  int v = (i < N) ? counts[i] : 0;
  int incl = v;
  #pragma unroll
  for (int off = 1; off < 64; off <<= 1) {
    int t = __shfl_up(incl, off, 64);
    if (lane >= off) incl += t;
  }
  if (lane == 63) wsum[wave] = incl;
  __syncthreads();
  if (wave == 0 && lane < 16) {
    int wincl = wsum[lane];
    #pragma unroll
    for (int off = 1; off < 16; off <<= 1) {
      int t = __shfl_up(wincl, off, 64);
      if (lane >= off) wincl += t;
    }
    wsum[lane] = wincl;
  }
  __syncthreads();
  int woff = (wave > 0) ? wsum[wave - 1] : 0;
  if (i < N) row_start[i] = woff + incl - v;  // tile-local exclusive
  if (tid == 0) btot[blockIdx.x] = wsum[15];
}

// Phase B: one wave scans block totals (nb <= 64); grand total -> row_start[N].
__global__ __launch_bounds__(64) void scanB_kernel(
    const int* __restrict__ btot, int* __restrict__ boff,
    int* __restrict__ row_start, int nb, int N) {
  int lane = threadIdx.x;
  int v = (lane < nb) ? btot[lane] : 0;
  int incl = v;
  #pragma unroll
  for (int off = 1; off < 64; off <<= 1) {
    int t = __shfl_up(incl, off, 64);
    if (lane >= off) incl += t;
  }
  if (lane < nb) boff[lane] = incl - v;
  if (lane == 63) row_start[N] = incl;
}

// Phase C: add block offsets.
__global__ __launch_bounds__(1024) void scanC_kernel(
    int* __restrict__ row_start, const int* __restrict__ boff, int N) {
  int i = blockIdx.x * 1024 + threadIdx.x;
  if (i < N) row_start[i] += boff[blockIdx.x];
}

// Atomic-free fill: one 8B packed (rcv,w) scatter per edge, 4 edges/thread.
__global__ __launch_bounds__(256) void fill_kernel(
    const vi4* __restrict__ snd4, const vi4* __restrict__ rcv4,
    const vf4* __restrict__ ew4, const vi4* __restrict__ pos4,
    const int* __restrict__ row_start, long long* __restrict__ pair,
    const int* __restrict__ snd, const int* __restrict__ rcv,
    const float* __restrict__ ew, const int* __restrict__ pos, int E) {
  int i = blockIdx.x * 256 + threadIdx.x;
  int E4 = E >> 2;
  if (i < E4) {
    vi4 s = __builtin_nontemporal_load(&snd4[i]);
    vi4 r = __builtin_nontemporal_load(&rcv4[i]);
    vf4 w = __builtin_nontemporal_load(&ew4[i]);
    vi4 p = __builtin_nontemporal_load(&pos4[i]);
    pair[row_start[s.x] + p.x] =
        (long long)(((unsigned long long)(unsigned)__float_as_int(w.x) << 32) | (unsigned)r.x);
    pair[row_start[s.y] + p.y] =
        (long long)(((unsigned long long)(unsigned)__float_as_int(w.y) << 32) | (unsigned)r.y);
    pair[row_start[s.z] + p.z] =
        (long long)(((unsigned long long)(unsigned)__float_as_int(w.z) << 32) | (unsigned)r.z);
    pair[row_start[s.w] + p.w] =
        (long long)(((unsigned long long)(unsigned)__float_as_int(w.w) << 32) | (unsigned)r.w);
  }
  if (i == 0) {  // scalar tail
    for (int e = E4 << 2; e < E; ++e) {
      pair[row_start[snd[e]] + pos[e]] =
          (long long)(((unsigned long long)(unsigned)__float_as_int(ew[e]) << 32) | (unsigned)rcv[e]);
    }
  }
}

__device__ __forceinline__ void edge_accum(
    float p0, float p1, float p2, float q0, float q1, float q2, float w,
    float& a0, float& a1, float& a2) {
  float cs = fminf(1.0f, fmaxf(-1.0f, fmaf(p0, q0, fmaf(p1, q1, p2 * q2))));
  float u0 = fmaf(-cs, p0, q0);
  float u1 = fmaf(-cs, p1, q1);
  float u2 = fmaf(-cs, p2, q2);
  // |u|^2 from components: no cancellation near cs=+-1, coef*u <= w*theta.
  float un2 = fmaxf(fmaf(u0, u0, fmaf(u1, u1, u2 * u2)), 1e-24f);
  // acos via A&S 4.4.45 (|err| <= 6.7e-5; output threshold is 2e-2)
  float ax = fabsf(cs);
  float s = sqrtf(1.0f - ax);
  float poly = fmaf(ax, fmaf(ax, fmaf(ax, -0.0187293f, 0.0742610f),
                             -0.2121144f), 1.5707288f);
  float th = s * poly;
  float theta = (cs >= 0.0f) ? th : (PI_F - th);
  float coef = w * theta * __builtin_amdgcn_rsqf(un2);
  a0 = fmaf(coef, u0, a0);
  a1 = fmaf(coef, u1, a1);
  a2 = fmaf(coef, u2, a2);
}

// One wave per node. lane = k*16 + c: channel c, edge-slot k.
// Per wave-iter: 8 edges (4 slots x 2-unroll) -> MLP, uniform trip count.
__global__ __launch_bounds__(256) void flow_kernel(
    const float* __restrict__ xin, const int* __restrict__ row_start,
    const long long* __restrict__ pair, const float* __restrict__ tsq,
    const float* __restrict__ dsq, float* __restrict__ xout, int N) {
  int node = blockIdx.x * 4 + (threadIdx.x >> 6);
  if (node >= N) return;
  int lane = threadIdx.x & 63;
  int c = lane & 15;
  int k = lane >> 4;
  int beg = row_start[node];
  int end = row_start[node + 1];
  int ip = node * 48 + c * 3;
  float p0 = xin[ip + 0], p1 = xin[ip + 1], p2 = xin[ip + 2];
  float a0 = 0.f, a1 = 0.f, a2 = 0.f, ws = 0.f;
  int iters = (end - beg + 7) >> 3;
  int lastj = end - 1;
  int j = beg + k;
  for (int t = 0; t < iters; ++t, j += 8) {
    int jA = j, jB = j + 4;
    long long eA = __builtin_nontemporal_load(&pair[min(jA, lastj)]);
    long long eB = __builtin_nontemporal_load(&pair[min(jB, lastj)]);
    int rA = (int)eA;
    int rB = (int)eB;
    float wA = (jA < end) ? __int_as_float((int)(eA >> 32)) : 0.f;
    float wB = (jB < end) ? __int_as_float((int)(eB >> 32)) : 0.f;
    const float* qA = xin + rA * 48 + c * 3;
    const float* qB = xin + rB * 48 + c * 3;
    float qA0 = qA[0], qA1 = qA[1], qA2 = qA[2];
    float qB0 = qB[0], qB1 = qB[1], qB2 = qB[2];
    edge_accum(p0, p1, p2, qA0, qA1, qA2, wA, a0, a1, a2);
    edge_accum(p0, p1, p2, qB0, qB1, qB2, wB, a0, a1, a2);
    ws += wA + wB;
  }
  // reduce edge-slots k=0..3 (lanes differing in bits 4,5)
  a0 += __shfl_xor(a0, 16); a1 += __shfl_xor(a1, 16);
  a2 += __shfl_xor(a2, 16); ws += __shfl_xor(ws, 16);
  a0 += __shfl_xor(a0, 32); a1 += __shfl_xor(a1, 32);
  a2 += __shfl_xor(a2, 32); ws += __shfl_xor(ws, 32);
  // v_lap = -agg/deg; nrm/scale sign-invariant; -(v_lap*scale)*t = +g*scale*t
  float invdg = __builtin_amdgcn_rcpf(ws + 1e-12f);
  float g0 = a0 * invdg, g1 = a1 * invdg, g2 = a2 * invdg;
  float nrm = sqrtf(fmaf(g0, g0, fmaf(g1, g1, g2 * g2)) + EPS64F);
  float ts = tsq[c];
  float tch = ts * ts * 0.5f;  // t_sqrt^2 / N_STEPS
  float dsv = dsq[c];
  float dch = dsv * dsv;
  float alp = __builtin_amdgcn_rcpf(1.0f + __expf(dch - nrm));  // sigmoid
  float scale = (nrm * alp <= 1.0f) ? alp : __builtin_amdgcn_rcpf(nrm);
  float f = scale * tch;
  float v0 = g0 * f, v1 = g1 * f, v2 = g2 * f;
  float nv = sqrtf(fmaf(v0, v0, fmaf(v1, v1, v2 * v2)));
  float cn = __cosf(nv);
  float sc = (nv > 1e-20f) ? (__sinf(nv) * __builtin_amdgcn_rcpf(nv)) : 1.0f;
  float y0 = fmaf(cn, p0, sc * v0);
  float y1 = fmaf(cn, p1, sc * v1);
  float y2 = fmaf(cn, p2, sc * v2);
  float inv = __builtin_amdgcn_rsqf(fmaf(y0, y0, fmaf(y1, y1, y2 * y2)));
  if (k == 0) {
    xout[ip + 0] = y0 * inv;
    xout[ip + 1] = y1 * inv;
    xout[ip + 2] = y2 * inv;
  }
}

extern "C" void kernel_launch(void* const* d_in, const int* in_sizes, int n_in,
                              void* d_out, int out_size, void* d_ws, size_t ws_size,
                              hipStream_t stream) {
  const float* nodes = (const float*)d_in[0];  // [N,16,3]
  const float* ew    = (const float*)d_in[1];  // [E]
  const float* tsq   = (const float*)d_in[2];  // [16]
  const float* dsq   = (const float*)d_in[3];  // [16]
  const int*   snd   = (const int*)d_in[4];    // [E]
  const int*   rcv   = (const int*)d_in[5];    // [E]
  float* out = (float*)d_out;

  int E = in_sizes[1];
  int N = in_sizes[0] / 48;

  // workspace (4-byte elems), padded so pair is 8B-aligned and pos 16B-aligned:
  // counts[N] | row_start[N+4] | btot[64] | boff[64] | pair[2E] | Z
  // Z union: pos[E] (hist->fill) and xtmp[N*48] (flow1->flow2)
  int*       counts    = (int*)d_ws;
  int*       row_start = counts + N;
  int*       btot      = row_start + (N + 4);
  int*       boff      = btot + 64;
  long long* pair      = (long long*)(boff + 64);
  int*       pos       = (int*)(pair + E);
  float*     xtmp      = (float*)pos;  // aliased; lifetimes disjoint

  hipMemsetAsync(counts, 0, sizeof(int) * (size_t)N, stream);

  int E4 = E >> 2;
  int eb = (E4 + 255) / 256;
  int nb = (N + 1023) / 1024;
  int fb = (N + 3) / 4;

  hist_kernel<<<eb, 256, 0, stream>>>((const vi4*)snd, counts, (vi4*)pos,
                                      snd, pos, E);
  scanA_kernel<<<nb, 1024, 0, stream>>>(counts, row_start, btot, N);
  scanB_kernel<<<1, 64, 0, stream>>>(btot, boff, row_start, nb, N);
  scanC_kernel<<<nb, 1024, 0, stream>>>(row_start, boff, N);
  fill_kernel<<<eb, 256, 0, stream>>>((const vi4*)snd, (const vi4*)rcv,
                                      (const vf4*)ew, (const vi4*)pos,
                                      row_start, pair, snd, rcv, ew, pos, E);

  // step 1: nodes -> xtmp ; step 2: xtmp -> out (not in-place: reads neighbors)
  flow_kernel<<<fb, 256, 0, stream>>>(nodes, row_start, pair, tsq, dsq, xtmp, N);
  flow_kernel<<<fb, 256, 0, stream>>>(xtmp, row_start, pair, tsq, dsq, out, N);
}

// Round 7
// 300.023 us; speedup vs baseline: 5.4815x; 1.0054x over previous
//
#include <hip/hip_runtime.h>
#include <math.h>

// FlowLayer: 2 steps of manifold (S^2) graph heat flow.
// N=50000 nodes, C=16 channels, D=3, E=1.6M edges.
// CSR build with 8-way privatized histogram (cuts per-counter atomic
// serialization 32->4): hist atomics into rep[r][s], r = blockIdx&7;
// scanA folds replicas (per-node per-replica exclusive prefix in place),
// scanC adds global row offsets into every replica entry, so fill's slot is
// rep[r][snd[e]] + pos[e] with a single random 4B load per edge.
// Flow: 1 wave per node, lane=(k*16+c), 8 edges/wave-iter, shfl_xor reduce.
// NOTE: |u|^2 MUST be computed from u's components (not 1-cs^2): near
// antipodal pairs 1-cs^2 cancels catastrophically -> rsq explodes (R5 bug).

constexpr float EPS64F = 2.2204460492503131e-16f;  // np.float64 eps
constexpr float PI_F   = 3.14159265358979323846f;
constexpr int   NREP   = 8;

typedef int   vi4 __attribute__((ext_vector_type(4)));
typedef float vf4 __attribute__((ext_vector_type(4)));

__global__ __launch_bounds__(256) void hist_kernel(
    const vi4* __restrict__ snd4, int* __restrict__ rep,
    vi4* __restrict__ pos4, const int* __restrict__ snd,
    int* __restrict__ pos, int N, int E) {
  int i = blockIdx.x * 256 + threadIdx.x;
  int rb = (blockIdx.x & (NREP - 1)) * N;  // replica base (match fill_kernel!)
  int E4 = E >> 2;
  if (i < E4) {
    vi4 s = __builtin_nontemporal_load(&snd4[i]);
    vi4 p;
    p.x = atomicAdd(&rep[rb + s.x], 1);
    p.y = atomicAdd(&rep[rb + s.y], 1);
    p.z = atomicAdd(&rep[rb + s.z], 1);
    p.w = atomicAdd(&rep[rb + s.w], 1);
    __builtin_nontemporal_store(p, &pos4[i]);
  }
  if (i == 0) {  // scalar tail (E % 4) -> replica 0
    for (int e = E4 << 2; e < E; ++e) pos[e] = atomicAdd(&rep[snd[e]], 1);
  }
}

// Phase A: fold 8 replicas per node (write exclusive prefix over replicas
// back in place), then per-1024-tile exclusive scan of node totals.
__global__ __launch_bounds__(1024) void scanA_kernel(
    int* __restrict__ rep, int* __restrict__ row_start,
    int* __restrict__ btot, int N) {
  __shared__ int wsum[16];
  int tid = threadIdx.x;
  int lane = tid & 63, wave = tid >> 6;
  int i = blockIdx.x * 1024 + tid;
  int v = 0;
  if (i < N) {
    int run = 0;
    int cpre[NREP];
    #pragma unroll
    for (int r = 0; r < NREP; ++r) {
      int t = rep[r * N + i];
      cpre[r] = run;  // exclusive over replicas
      run += t;
    }
    v = run;  // node total
    #pragma unroll
    for (int r = 0; r < NREP; ++r) rep[r * N + i] = cpre[r];
  }
  int incl = v;
  #pragma unroll
  for (int off = 1; off < 64; off <<= 1) {
    int t = __shfl_up(incl, off, 64);
    if (lane >= off) incl += t;
  }
  if (lane == 63) wsum[wave] = incl;
  __syncthreads();
  if (wave == 0 && lane < 16) {
    int wincl = wsum[lane];
    #pragma unroll
    for (int off = 1; off < 16; off <<= 1) {
      int t = __shfl_up(wincl, off, 64);
      if (lane >= off) wincl += t;
    }
    wsum[lane] = wincl;
  }
  __syncthreads();
  int woff = (wave > 0) ? wsum[wave - 1] : 0;
  if (i < N) row_start[i] = woff + incl - v;  // tile-local exclusive
  if (tid == 0) btot[blockIdx.x] = wsum[15];
}

// Phase B: one wave scans block totals (nb <= 64); grand total -> row_start[N].
__global__ __launch_bounds__(64) void scanB_kernel(
    const int* __restrict__ btot, int* __restrict__ boff,
    int* __restrict__ row_start, int nb, int N) {
  int lane = threadIdx.x;
  int v = (lane < nb) ? btot[lane] : 0;
  int incl = v;
  #pragma unroll
  for (int off = 1; off < 64; off <<= 1) {
    int t = __shfl_up(incl, off, 64);
    if (lane >= off) incl += t;
  }
  if (lane < nb) boff[lane] = incl - v;
  if (lane == 63) row_start[N] = incl;
}

// Phase C: finalize row_start and push global offsets into every replica.
__global__ __launch_bounds__(1024) void scanC_kernel(
    int* __restrict__ row_start, const int* __restrict__ boff,
    int* __restrict__ rep, int N) {
  int i = blockIdx.x * 1024 + threadIdx.x;
  if (i < N) {
    int rs = row_start[i] + boff[blockIdx.x];
    row_start[i] = rs;
    #pragma unroll
    for (int r = 0; r < NREP; ++r) rep[r * N + i] += rs;
  }
}

// Atomic-free fill: slot = rep[r][snd] + pos; one 8B packed scatter per edge.
__global__ __launch_bounds__(256) void fill_kernel(
    const vi4* __restrict__ snd4, const vi4* __restrict__ rcv4,
    const vf4* __restrict__ ew4, const vi4* __restrict__ pos4,
    const int* __restrict__ rep, long long* __restrict__ pair,
    const int* __restrict__ snd, const int* __restrict__ rcv,
    const float* __restrict__ ew, const int* __restrict__ pos, int N, int E) {
  int i = blockIdx.x * 256 + threadIdx.x;
  int rb = (blockIdx.x & (NREP - 1)) * N;  // must match hist_kernel
  int E4 = E >> 2;
  if (i < E4) {
    vi4 s = __builtin_nontemporal_load(&snd4[i]);
    vi4 r = __builtin_nontemporal_load(&rcv4[i]);
    vf4 w = __builtin_nontemporal_load(&ew4[i]);
    vi4 p = __builtin_nontemporal_load(&pos4[i]);
    pair[rep[rb + s.x] + p.x] =
        (long long)(((unsigned long long)(unsigned)__float_as_int(w.x) << 32) | (unsigned)r.x);
    pair[rep[rb + s.y] + p.y] =
        (long long)(((unsigned long long)(unsigned)__float_as_int(w.y) << 32) | (unsigned)r.y);
    pair[rep[rb + s.z] + p.z] =
        (long long)(((unsigned long long)(unsigned)__float_as_int(w.z) << 32) | (unsigned)r.z);
    pair[rep[rb + s.w] + p.w] =
        (long long)(((unsigned long long)(unsigned)__float_as_int(w.w) << 32) | (unsigned)r.w);
  }
  if (i == 0) {  // scalar tail -> replica 0
    for (int e = E4 << 2; e < E; ++e) {
      pair[rep[snd[e]] + pos[e]] =
          (long long)(((unsigned long long)(unsigned)__float_as_int(ew[e]) << 32) | (unsigned)rcv[e]);
    }
  }
}

__device__ __forceinline__ void edge_accum(
    float p0, float p1, float p2, float q0, float q1, float q2, float w,
    float& a0, float& a1, float& a2) {
  float cs = fminf(1.0f, fmaxf(-1.0f, fmaf(p0, q0, fmaf(p1, q1, p2 * q2))));
  float u0 = fmaf(-cs, p0, q0);
  float u1 = fmaf(-cs, p1, q1);
  float u2 = fmaf(-cs, p2, q2);
  // |u|^2 from components: no cancellation near cs=+-1, coef*u <= w*theta.
  float un2 = fmaxf(fmaf(u0, u0, fmaf(u1, u1, u2 * u2)), 1e-24f);
  // acos via A&S 4.4.45 (|err| <= 6.7e-5; output threshold is 2e-2)
  float ax = fabsf(cs);
  float s = sqrtf(1.0f - ax);
  float poly = fmaf(ax, fmaf(ax, fmaf(ax, -0.0187293f, 0.0742610f),
                             -0.2121144f), 1.5707288f);
  float th = s * poly;
  float theta = (cs >= 0.0f) ? th : (PI_F - th);
  float coef = w * theta * __builtin_amdgcn_rsqf(un2);
  a0 = fmaf(coef, u0, a0);
  a1 = fmaf(coef, u1, a1);
  a2 = fmaf(coef, u2, a2);
}

// One wave per node. lane = k*16 + c: channel c, edge-slot k.
// Per wave-iter: 8 edges (4 slots x 2-unroll) -> MLP, uniform trip count.
__global__ __launch_bounds__(256) void flow_kernel(
    const float* __restrict__ xin, const int* __restrict__ row_start,
    const long long* __restrict__ pair, const float* __restrict__ tsq,
    const float* __restrict__ dsq, float* __restrict__ xout, int N) {
  int node = blockIdx.x * 4 + (threadIdx.x >> 6);
  if (node >= N) return;
  int lane = threadIdx.x & 63;
  int c = lane & 15;
  int k = lane >> 4;
  int beg = row_start[node];
  int end = row_start[node + 1];
  int ip = node * 48 + c * 3;
  float p0 = xin[ip + 0], p1 = xin[ip + 1], p2 = xin[ip + 2];
  float a0 = 0.f, a1 = 0.f, a2 = 0.f, ws = 0.f;
  int iters = (end - beg + 7) >> 3;
  int lastj = end - 1;
  int j = beg + k;
  for (int t = 0; t < iters; ++t, j += 8) {
    int jA = j, jB = j + 4;
    long long eA = __builtin_nontemporal_load(&pair[min(jA, lastj)]);
    long long eB = __builtin_nontemporal_load(&pair[min(jB, lastj)]);
    int rA = (int)eA;
    int rB = (int)eB;
    float wA = (jA < end) ? __int_as_float((int)(eA >> 32)) : 0.f;
    float wB = (jB < end) ? __int_as_float((int)(eB >> 32)) : 0.f;
    const float* qA = xin + rA * 48 + c * 3;
    const float* qB = xin + rB * 48 + c * 3;
    float qA0 = qA[0], qA1 = qA[1], qA2 = qA[2];
    float qB0 = qB[0], qB1 = qB[1], qB2 = qB[2];
    edge_accum(p0, p1, p2, qA0, qA1, qA2, wA, a0, a1, a2);
    edge_accum(p0, p1, p2, qB0, qB1, qB2, wB, a0, a1, a2);
    ws += wA + wB;
  }
  // reduce edge-slots k=0..3 (lanes differing in bits 4,5)
  a0 += __shfl_xor(a0, 16); a1 += __shfl_xor(a1, 16);
  a2 += __shfl_xor(a2, 16); ws += __shfl_xor(ws, 16);
  a0 += __shfl_xor(a0, 32); a1 += __shfl_xor(a1, 32);
  a2 += __shfl_xor(a2, 32); ws += __shfl_xor(ws, 32);
  // v_lap = -agg/deg; nrm/scale sign-invariant; -(v_lap*scale)*t = +g*scale*t
  float invdg = __builtin_amdgcn_rcpf(ws + 1e-12f);
  float g0 = a0 * invdg, g1 = a1 * invdg, g2 = a2 * invdg;
  float nrm = sqrtf(fmaf(g0, g0, fmaf(g1, g1, g2 * g2)) + EPS64F);
  float ts = tsq[c];
  float tch = ts * ts * 0.5f;  // t_sqrt^2 / N_STEPS
  float dsv = dsq[c];
  float dch = dsv * dsv;
  float alp = __builtin_amdgcn_rcpf(1.0f + __expf(dch - nrm));  // sigmoid
  float scale = (nrm * alp <= 1.0f) ? alp : __builtin_amdgcn_rcpf(nrm);
  float f = scale * tch;
  float v0 = g0 * f, v1 = g1 * f, v2 = g2 * f;
  float nv = sqrtf(fmaf(v0, v0, fmaf(v1, v1, v2 * v2)));
  float cn = __cosf(nv);
  float sc = (nv > 1e-20f) ? (__sinf(nv) * __builtin_amdgcn_rcpf(nv)) : 1.0f;
  float y0 = fmaf(cn, p0, sc * v0);
  float y1 = fmaf(cn, p1, sc * v1);
  float y2 = fmaf(cn, p2, sc * v2);
  float inv = __builtin_amdgcn_rsqf(fmaf(y0, y0, fmaf(y1, y1, y2 * y2)));
  if (k == 0) {
    xout[ip + 0] = y0 * inv;
    xout[ip + 1] = y1 * inv;
    xout[ip + 2] = y2 * inv;
  }
}

extern "C" void kernel_launch(void* const* d_in, const int* in_sizes, int n_in,
                              void* d_out, int out_size, void* d_ws, size_t ws_size,
                              hipStream_t stream) {
  const float* nodes = (const float*)d_in[0];  // [N,16,3]
  const float* ew    = (const float*)d_in[1];  // [E]
  const float* tsq   = (const float*)d_in[2];  // [16]
  const float* dsq   = (const float*)d_in[3];  // [16]
  const int*   snd   = (const int*)d_in[4];    // [E]
  const int*   rcv   = (const int*)d_in[5];    // [E]
  float* out = (float*)d_out;

  int E = in_sizes[1];
  int N = in_sizes[0] / 48;

  // workspace (4-byte elems):
  // rep[8*N] | row_start[N+4] | btot[64] | boff[64] | pair[2E] | Z
  // Z union: pos[E] (hist->fill) and xtmp[N*48] (flow1->flow2)
  int*       rep       = (int*)d_ws;
  int*       row_start = rep + NREP * N;
  int*       btot      = row_start + (N + 4);
  int*       boff      = btot + 64;
  long long* pair      = (long long*)(boff + 64);
  int*       pos       = (int*)(pair + E);
  float*     xtmp      = (float*)pos;  // aliased; lifetimes disjoint

  hipMemsetAsync(rep, 0, sizeof(int) * (size_t)(NREP * N), stream);

  int E4 = E >> 2;
  int eb = (E4 + 255) / 256;
  int nb = (N + 1023) / 1024;
  int fb = (N + 3) / 4;

  hist_kernel<<<eb, 256, 0, stream>>>((const vi4*)snd, rep, (vi4*)pos,
                                      snd, pos, N, E);
  scanA_kernel<<<nb, 1024, 0, stream>>>(rep, row_start, btot, N);
  scanB_kernel<<<1, 64, 0, stream>>>(btot, boff, row_start, nb, N);
  scanC_kernel<<<nb, 1024, 0, stream>>>(row_start, boff, rep, N);
  fill_kernel<<<eb, 256, 0, stream>>>((const vi4*)snd, (const vi4*)rcv,
                                      (const vf4*)ew, (const vi4*)pos,
                                      rep, pair, snd, rcv, ew, pos, N, E);

  // step 1: nodes -> xtmp ; step 2: xtmp -> out (not in-place: reads neighbors)
  flow_kernel<<<fb, 256, 0, stream>>>(nodes, row_start, pair, tsq, dsq, xtmp, N);
  flow_kernel<<<fb, 256, 0, stream>>>(xtmp, row_start, pair, tsq, dsq, out, N);
}